// Round 1
// 659.501 us; speedup vs baseline: 1.2146x; 1.2146x over previous
//
#include <hip/hip_runtime.h>
#include <math.h>

// Problem constants
#define TT    48
#define BB    96
#define DG    192
#define DH    384
#define DHP   388    // padded hist row stride (floats): 1552 B -> groups hit distinct banks
#define NSTEP 47     // T-1 scan steps
#define SETI  3      // inner settling iterations
#define NT    768    // threads per block
#define NWAVE 12     // 768/64
#define NOW   6      // owner waves (tid < DH)
#define NG    48     // 16-lane groups per block

typedef unsigned short ushort_t;

// ---------- DPP-based reductions (VALU latency, not LDS latency) ----------
template <int CTRL, int RM>
__device__ __forceinline__ float dppadd(float acc, float x) {
  int t = __builtin_amdgcn_update_dpp(0, __float_as_int(x), CTRL, RM, 0xF, false);
  return acc + __int_as_float(t);
}

// Sum of 16 lanes within each row; every lane of the row gets the total.
__device__ __forceinline__ float row16_sum(float v) {
  v = dppadd<0x128, 0xF>(v, v);  // row_ror:8
  v = dppadd<0x124, 0xF>(v, v);  // row_ror:4
  v = dppadd<0x122, 0xF>(v, v);  // row_ror:2
  v = dppadd<0x121, 0xF>(v, v);  // row_ror:1
  return v;
}

// Full wave64 sum; lane 63 holds the total.
__device__ __forceinline__ float wave_sum63(float v) {
  v = row16_sum(v);
  v = dppadd<0x142, 0xA>(v, v);  // row_bcast:15 -> rows 1,3
  v = dppadd<0x143, 0xC>(v, v);  // row_bcast:31 -> rows 2,3
  return v;
}

__device__ __forceinline__ float blo(unsigned u) {
  return __uint_as_float(u << 16);
}
__device__ __forceinline__ float bhi(unsigned u) {
  return __uint_as_float(u & 0xFFFF0000u);
}

// matvec: hbs[r] = W_g[r,:].z + (with_h ? W_h[r,:].hprev : 0) + bias.
// 16-lane group g handles rows r = p*48+g. Also accumulates per-thread
// partial LN stats (s1 += hb, s2 += hb^2) on lane16==0 threads.
template <bool BF16W>
__device__ __forceinline__ void matvec(
    const float* __restrict__ Wh_f, const float* __restrict__ Wg_f,
    const ushort_t* __restrict__ Wh_b, const ushort_t* __restrict__ Wg_b,
    const float* __restrict__ hprev, const float* __restrict__ zsh,
    const float (&bias)[8], float* __restrict__ hbs,
    float& s1, float& s2, int g, int lane16, bool with_h)
{
  const float4* z4 = (const float4*)zsh;
  const float4* h4 = (const float4*)hprev;
#pragma unroll 2
  for (int p = 0; p < 8; ++p) {
    const int r = p * NG + g;
    float a0 = 0.f, a1 = 0.f;
    if (BF16W) {
      const uint2* wg = (const uint2*)Wg_b + (size_t)r * (DG / 4);
#pragma unroll
      for (int c = 0; c < 3; ++c) {
        uint2 u = wg[lane16 + 16 * c];
        float4 z = z4[lane16 + 16 * c];
        a0 = fmaf(blo(u.x), z.x, a0); a0 = fmaf(bhi(u.x), z.y, a0);
        a1 = fmaf(blo(u.y), z.z, a1); a1 = fmaf(bhi(u.y), z.w, a1);
      }
      if (with_h) {
        const uint4* wh = (const uint4*)Wh_b + (size_t)r * (DH / 8);
#pragma unroll
        for (int c = 0; c < 3; ++c) {
          uint4 u = wh[lane16 + 16 * c];
          float4 ha = h4[(lane16 + 16 * c) * 2];
          float4 hb2 = h4[(lane16 + 16 * c) * 2 + 1];
          a0 = fmaf(blo(u.x), ha.x, a0);  a0 = fmaf(bhi(u.x), ha.y, a0);
          a1 = fmaf(blo(u.y), ha.z, a1);  a1 = fmaf(bhi(u.y), ha.w, a1);
          a0 = fmaf(blo(u.z), hb2.x, a0); a0 = fmaf(bhi(u.z), hb2.y, a0);
          a1 = fmaf(blo(u.w), hb2.z, a1); a1 = fmaf(bhi(u.w), hb2.w, a1);
        }
      }
    } else {
      const float4* wg = (const float4*)Wg_f + (size_t)r * (DG / 4);
#pragma unroll
      for (int c = 0; c < 3; ++c) {
        float4 w = wg[lane16 + 16 * c], z = z4[lane16 + 16 * c];
        a0 = fmaf(w.x, z.x, a0); a0 = fmaf(w.y, z.y, a0);
        a1 = fmaf(w.z, z.z, a1); a1 = fmaf(w.w, z.w, a1);
      }
      if (with_h) {
        const float4* wh = (const float4*)Wh_f + (size_t)r * (DH / 4);
#pragma unroll
        for (int c = 0; c < 6; ++c) {
          float4 w = wh[lane16 + 16 * c], h = h4[lane16 + 16 * c];
          a0 = fmaf(w.x, h.x, a0); a0 = fmaf(w.y, h.y, a0);
          a1 = fmaf(w.z, h.z, a1); a1 = fmaf(w.w, h.w, a1);
        }
      }
    }
    float acc = row16_sum(a0 + a1);
    if (lane16 == 0) {
      float vv = acc + bias[p];
      hbs[r] = vv;
      s1 += vv;
      s2 += vv * vv;
    }
  }
}

template <bool BF16W>
__global__ __launch_bounds__(NT) void fw_rnn_kernel(
    const float* __restrict__ z_seq,    // [T, B, DG]
    const float* __restrict__ Wh_f,     // [DH, DH] fp32
    const float* __restrict__ Wg_f,     // [DH, DG] fp32
    const ushort_t* __restrict__ Wh_b,  // bf16 copies (in ws)
    const ushort_t* __restrict__ Wg_b,
    const float* __restrict__ b_h,
    const float* __restrict__ ln_g,
    const float* __restrict__ ln_b,
    const float* __restrict__ alpha_fw,
    float* __restrict__ out)            // [B, DH]
{
  __shared__ __align__(16) float hist[NSTEP * DHP];
  __shared__ __align__(16) float hs[DH];
  __shared__ __align__(16) float zsh[DG];
  __shared__ __align__(16) float hbs[DH];
  __shared__ float wlam[NSTEP];
  __shared__ __align__(16) float carr[NG];
  __shared__ float redA[NWAVE * 2];
  __shared__ float redB[2][NOW * 5];

  const int tid    = threadIdx.x;
  const int b      = blockIdx.x;
  const int lane   = tid & 63, wv = tid >> 6;
  const int g      = tid >> 4, lane16 = tid & 15;
  const bool owner = (tid < DH);
  const bool zst   = (tid >= DH) && (tid < DH + DG / 4);

  float bias[8];
#pragma unroll
  for (int p = 0; p < 8; ++p) bias[p] = 0.f;
  if (lane16 == 0) {
#pragma unroll
    for (int p = 0; p < 8; ++p) bias[p] = b_h[p * NG + g];
  }
  float g_i = 0.f, be_i = 0.f;
  if (owner) { g_i = ln_g[tid]; be_i = ln_b[tid]; }

  const float af   = alpha_fw[0];
  const float kcur = (af >= 0.f) ? (1.f + log1pf(expf(af)))
                                 : (1.f / (1.f + log1pf(expf(-af))));
  const float invD = 1.0f / (float)DH;

  // Register-resident history column: hcol[tau] == hist[tau][tid] for owners.
  // Entries never committed stay 0 so the always-48-wide phase-B dot is exact.
  float hcol[48];
#pragma unroll
  for (int q = 0; q < 48; ++q) hcol[q] = 0.f;

  // stage z_0; zero carr (entries >= t are read by the 48-wide dot)
  if (tid < DG / 4)
    ((float4*)zsh)[tid] = ((const float4*)(z_seq + (size_t)b * DG))[tid];
  if (tid < NG) carr[tid] = 0.f;
  __syncthreads();

  float Shb = 0.f, Shb2 = 0.f;

  for (int t = 0; t < NSTEP; ++t) {
    // ---------- base phase: h_base + fused LN stats ----------
    float s1 = 0.f, s2 = 0.f;
    matvec<BF16W>(Wh_f, Wg_f, Wh_b, Wg_b,
                  hist + (size_t)(t > 0 ? t - 1 : 0) * DHP, zsh, bias, hbs,
                  s1, s2, g, lane16, t > 0);
    {
      float v0 = wave_sum63(s1);
      float v1 = wave_sum63(s2);
      if (lane == 63) { redA[wv * 2] = v0; redA[wv * 2 + 1] = v1; }
    }
    __syncthreads();  // (a): hbs + redA visible

    float hb = 0.f, hsv = 0.f;
    {
      float S1 = 0.f, S2 = 0.f;
#pragma unroll
      for (int w = 0; w < NWAVE; ++w) { S1 += redA[w * 2]; S2 += redA[w * 2 + 1]; }
      Shb = S1; Shb2 = S2;
      if (owner) {
        hb = hbs[tid];
        float m   = S1 * invD;
        float var = S2 * invD - m * m;
        hsv = fmaxf((hb - m) * rsqrtf(var + 1e-5f) * g_i + be_i, 0.f);
        hs[tid] = hsv;
      }
    }
    if (t == 0) {
      // A == 0: settling is identity. Commit, init wlam, stage z_1.
      if (owner) { hist[tid] = hsv; hcol[0] = hsv; }
      if (tid == 0) wlam[0] = 0.5f;
      if (zst)
        ((float4*)zsh)[tid - DH] =
            ((const float4*)(z_seq + ((size_t)1 * BB + b) * DG))[tid - DH];
      __syncthreads();  // (b)
      continue;
    }
    __syncthreads();  // (b): hs visible

    // prefetch z_{t+1} to a register; LDS-write happens at commit so the
    // commit barrier's vmcnt(0) does not wait on L2.
    float4 znext;
    if (zst)
      znext = ((const float4*)(z_seq + ((size_t)(t + 1) * BB + b) * DG))[tid - DH];

    // ---------- settling iterations ----------
    for (int s = 0; s < SETI; ++s) {
      // phase A: d_tau = wlam_tau * (h_tau . h_s), one 16-lane group per tau
      if (g < t) {
        const float4* h4 = (const float4*)(hist + (size_t)g * DHP);
        const float4* s4 = (const float4*)hs;
        float p0 = 0.f, p1 = 0.f;
#pragma unroll
        for (int kk = 0; kk < 6; kk += 2) {
          float4 ha = h4[lane16 + 16 * kk],       sa = s4[lane16 + 16 * kk];
          float4 hbb = h4[lane16 + 16 * (kk + 1)], sb = s4[lane16 + 16 * (kk + 1)];
          p0 = fmaf(ha.x, sa.x, p0); p0 = fmaf(ha.y, sa.y, p0);
          p0 = fmaf(ha.z, sa.z, p0); p0 = fmaf(ha.w, sa.w, p0);
          p1 = fmaf(hbb.x, sb.x, p1); p1 = fmaf(hbb.y, sb.y, p1);
          p1 = fmaf(hbb.z, sb.z, p1); p1 = fmaf(hbb.w, sb.w, p1);
        }
        float p = row16_sum(p0 + p1);
        if (lane16 == 0) carr[g] = p * wlam[g];
      }
      __syncthreads();  // (i): carr visible

      // phase B: owners compute Ah from registers + 5 partial sums via DPP
      float ah = 0.f;
      if (owner) {
        const float4* c4 = (const float4*)carr;
        float ah0 = 0.f, ah1 = 0.f, ah2 = 0.f, ah3 = 0.f;
#pragma unroll
        for (int q = 0; q < 12; ++q) {
          float4 c = c4[q];
          ah0 = fmaf(c.x, hcol[4 * q + 0], ah0);
          ah1 = fmaf(c.y, hcol[4 * q + 1], ah1);
          ah2 = fmaf(c.z, hcol[4 * q + 2], ah2);
          ah3 = fmaf(c.w, hcol[4 * q + 3], ah3);
        }
        ah = (ah0 + ah2) + (ah1 + ah3);
        float v0 = wave_sum63(hsv * ah);
        float v1 = wave_sum63(hsv * hsv);
        float v2 = wave_sum63(ah * ah);
        float v3 = wave_sum63(hb * ah);
        float v4 = wave_sum63(ah);
        if (lane == 63) {
          float* rb = redB[s & 1];
          rb[wv * 5 + 0] = v0; rb[wv * 5 + 1] = v1; rb[wv * 5 + 2] = v2;
          rb[wv * 5 + 3] = v3; rb[wv * 5 + 4] = v4;
        }
      }
      __syncthreads();  // (ii): redB visible

      // phase C: gate + analytic LN + commit
      if (owner) {
        const float* rb = redB[s & 1];
        float S0 = 0, S1 = 0, S2 = 0, S3 = 0, S4 = 0;
#pragma unroll
        for (int w = 0; w < NOW; ++w) {
          S0 += rb[w * 5 + 0]; S1 += rb[w * 5 + 1]; S2 += rb[w * 5 + 2];
          S3 += rb[w * 5 + 3]; S4 += rb[w * 5 + 4];
        }
        float n1 = fmaxf(sqrtf(S1), 1e-6f);
        float n2 = fmaxf(sqrtf(S2), 1e-6f);
        float R  = fminf(fmaxf(__fdividef(S0, n1 * n2), 0.f), 1.f);
        // a = 1 - (1-R)^k via hw log/exp; exact at R=0 (a=0) and R=1 (a=1)
        float a  = 1.f - __expf(kcur * __logf(1.f - R));
        float beta = 1.f - a * a;
        float mu  = (beta * Shb + a * S4) * invD;
        float Exx = (beta * beta * Shb2 + 2.f * beta * a * S3 + a * a * S2) * invD;
        float var = Exx - mu * mu;
        float xv  = beta * hb + a * ah;
        hsv = fmaxf((xv - mu) * rsqrtf(var + 1e-5f) * g_i + be_i, 0.f);
        hs[tid] = hsv;
        if (s == SETI - 1) {
          hist[(size_t)t * DHP + tid] = hsv;
#pragma unroll
          for (int q = 0; q < 48; ++q)
            if (q == t) hcol[q] = hsv;
        }
      }
      if (s == SETI - 1) {
        if (tid < t) wlam[tid] *= 0.9f;
        else if (tid == t) wlam[tid] = 0.5f;
        if (zst) ((float4*)zsh)[tid - DH] = znext;
      }
      __syncthreads();  // (iii)
    }
  }

  // ================= final (query) step =================
  {
    float s1 = 0.f, s2 = 0.f;
    matvec<BF16W>(Wh_f, Wg_f, Wh_b, Wg_b,
                  hist + (size_t)(NSTEP - 1) * DHP, zsh, bias, hbs,
                  s1, s2, g, lane16, true);
    {
      float v0 = wave_sum63(s1);
      float v1 = wave_sum63(s2);
      if (lane == 63) { redA[wv * 2] = v0; redA[wv * 2 + 1] = v1; }
    }
    __syncthreads();

    float hb = 0.f, hv = 0.f;
    {
      float S1 = 0.f, S2 = 0.f;
#pragma unroll
      for (int w = 0; w < NWAVE; ++w) { S1 += redA[w * 2]; S2 += redA[w * 2 + 1]; }
      Shb = S1; Shb2 = S2;
      if (owner) {
        hb = hbs[tid];
        float m   = S1 * invD;
        float var = S2 * invD - m * m;
        hv = fmaxf((hb - m) * rsqrtf(var + 1e-5f) * g_i + be_i, 0.f);
        hs[tid] = hv;
      }
    }
    __syncthreads();

    for (int s = 0; s < SETI; ++s) {
      if (g < NSTEP) {
        const float4* h4 = (const float4*)(hist + (size_t)g * DHP);
        const float4* s4 = (const float4*)hs;
        float p0 = 0.f, p1 = 0.f;
#pragma unroll
        for (int kk = 0; kk < 6; kk += 2) {
          float4 ha = h4[lane16 + 16 * kk],       sa = s4[lane16 + 16 * kk];
          float4 hbb = h4[lane16 + 16 * (kk + 1)], sb = s4[lane16 + 16 * (kk + 1)];
          p0 = fmaf(ha.x, sa.x, p0); p0 = fmaf(ha.y, sa.y, p0);
          p0 = fmaf(ha.z, sa.z, p0); p0 = fmaf(ha.w, sa.w, p0);
          p1 = fmaf(hbb.x, sb.x, p1); p1 = fmaf(hbb.y, sb.y, p1);
          p1 = fmaf(hbb.z, sb.z, p1); p1 = fmaf(hbb.w, sb.w, p1);
        }
        float p = row16_sum(p0 + p1);
        if (lane16 == 0) carr[g] = p * wlam[g];
      }
      __syncthreads();

      float ah = 0.f;
      if (owner) {
        const float4* c4 = (const float4*)carr;
        float ah0 = 0.f, ah1 = 0.f, ah2 = 0.f, ah3 = 0.f;
#pragma unroll
        for (int q = 0; q < 12; ++q) {
          float4 c = c4[q];
          ah0 = fmaf(c.x, hcol[4 * q + 0], ah0);
          ah1 = fmaf(c.y, hcol[4 * q + 1], ah1);
          ah2 = fmaf(c.z, hcol[4 * q + 2], ah2);
          ah3 = fmaf(c.w, hcol[4 * q + 3], ah3);
        }
        ah = (ah0 + ah2) + (ah1 + ah3);
        float v0 = wave_sum63(ah);
        float v1 = wave_sum63(ah * ah);
        float v2 = wave_sum63(hb * ah);
        if (lane == 63) {
          float* rb = redB[s & 1];
          rb[wv * 5 + 0] = v0; rb[wv * 5 + 1] = v1; rb[wv * 5 + 2] = v2;
        }
      }
      __syncthreads();

      if (owner) {
        const float* rb = redB[s & 1];
        float S0 = 0, S1 = 0, S2 = 0;
#pragma unroll
        for (int w = 0; w < NOW; ++w) {
          S0 += rb[w * 5 + 0]; S1 += rb[w * 5 + 1]; S2 += rb[w * 5 + 2];
        }
        // xv = hb + ah : analytic stats
        float Sx  = Shb + S0;
        float Sxx = Shb2 + 2.f * S2 + S1;
        float mu  = Sx * invD;
        float var = Sxx * invD - mu * mu;
        float xv  = hb + ah;
        hv = fmaxf((xv - mu) * rsqrtf(var + 1e-5f) * g_i + be_i, 0.f);
        if (s < SETI - 1) hs[tid] = hv;
      }
      if (s < SETI - 1) __syncthreads();
    }

    if (owner) out[(size_t)b * DH + tid] = hv;
  }
}

// fp32 -> bf16 (RTN-even) conversion for W matrices
__global__ void cvt_kernel(const float* __restrict__ src,
                           ushort_t* __restrict__ dst, int n) {
  int i = blockIdx.x * blockDim.x + threadIdx.x;
  if (i < n) {
    unsigned u = __float_as_uint(src[i]);
    unsigned r = (u + 0x7FFFu + ((u >> 16) & 1u)) >> 16;
    dst[i] = (ushort_t)r;
  }
}

extern "C" void kernel_launch(void* const* d_in, const int* in_sizes, int n_in,
                              void* d_out, int out_size, void* d_ws, size_t ws_size,
                              hipStream_t stream) {
  const float* z_seq    = (const float*)d_in[0];
  const float* W_h      = (const float*)d_in[1];
  const float* W_g      = (const float*)d_in[2];
  const float* b_h      = (const float*)d_in[3];
  const float* ln_g     = (const float*)d_in[4];
  const float* ln_b     = (const float*)d_in[5];
  const float* alpha_fw = (const float*)d_in[6];
  float* out = (float*)d_out;

  const size_t nWh = (size_t)DH * DH;  // 147456
  const size_t nWg = (size_t)DH * DG;  // 73728

  if (ws_size >= (nWh + nWg) * sizeof(ushort_t)) {
    ushort_t* Whb = (ushort_t*)d_ws;
    ushort_t* Wgb = Whb + nWh;
    cvt_kernel<<<dim3((int)((nWh + 255) / 256)), dim3(256), 0, stream>>>(
        W_h, Whb, (int)nWh);
    cvt_kernel<<<dim3((int)((nWg + 255) / 256)), dim3(256), 0, stream>>>(
        W_g, Wgb, (int)nWg);
    fw_rnn_kernel<true><<<dim3(BB), dim3(NT), 0, stream>>>(
        z_seq, W_h, W_g, Whb, Wgb, b_h, ln_g, ln_b, alpha_fw, out);
  } else {
    fw_rnn_kernel<false><<<dim3(BB), dim3(NT), 0, stream>>>(
        z_seq, W_h, W_g, nullptr, nullptr, b_h, ln_g, ln_b, alpha_fw, out);
  }
}

// Round 2
// 573.834 us; speedup vs baseline: 1.3959x; 1.1493x over previous
//
#include <hip/hip_runtime.h>
#include <math.h>

// Problem constants
#define TT    48
#define BB    96
#define DG    192
#define DH    384
#define NSTEP 47     // T-1 scan steps
#define SETI  3      // inner settling iterations
#define NT    768    // threads per block
#define NWAVE 12     // 768/64
#define NOW   6      // owner waves (tid < DH)
#define NG    48     // 16-lane groups per block

typedef unsigned short ushort_t;
typedef float f32x2 __attribute__((ext_vector_type(2)));

// ---------- DPP-based reductions (VALU latency, not LDS latency) ----------
template <int CTRL, int RM>
__device__ __forceinline__ float dppadd(float acc, float x) {
  int t = __builtin_amdgcn_update_dpp(0, __float_as_int(x), CTRL, RM, 0xF, false);
  return acc + __int_as_float(t);
}

// Sum of 16 lanes within each row; every lane of the row gets the total.
__device__ __forceinline__ float row16_sum(float v) {
  v = dppadd<0x128, 0xF>(v, v);  // row_ror:8
  v = dppadd<0x124, 0xF>(v, v);  // row_ror:4
  v = dppadd<0x122, 0xF>(v, v);  // row_ror:2
  v = dppadd<0x121, 0xF>(v, v);  // row_ror:1
  return v;
}

// Full wave64 sum; lane 63 holds the total.
__device__ __forceinline__ float wave_sum63(float v) {
  v = row16_sum(v);
  v = dppadd<0x142, 0xA>(v, v);  // row_bcast:15 -> rows 1,3
  v = dppadd<0x143, 0xC>(v, v);  // row_bcast:31 -> rows 2,3
  return v;
}

__device__ __forceinline__ float blo(unsigned u) {
  return __uint_as_float(u << 16);
}
__device__ __forceinline__ float bhi(unsigned u) {
  return __uint_as_float(u & 0xFFFF0000u);
}
__device__ __forceinline__ f32x2 pkfma(f32x2 a, f32x2 b, f32x2 c) {
  return __builtin_elementwise_fma(a, b, c);
}

// matvec for one step:
//   FULL : hbs[r] = bf16(W_h)[r,:].hprev + gzrow[r]           (gz has Wg.z + b_h)
//   !FULL: hbs[r] = f32 W_h[r,:].hprev + f32 W_g[r,:].z + bias
// 16-lane group g handles rows r = p*48+g. lane16==0 accumulates LN stats.
template <bool FULL>
__device__ __forceinline__ void matvec(
    const float* __restrict__ Wh_f, const float* __restrict__ Wg_f,
    const ushort_t* __restrict__ Wh_b,
    const float* __restrict__ hprev, const float* __restrict__ zsh,
    const float* __restrict__ gzrow,
    const float (&bias)[8], float* __restrict__ hbs,
    float& s1, float& s2, int g, int lane16, bool with_h)
{
  f32x2 h2[12];
  if (with_h) {
    const float4* h4 = (const float4*)hprev;
#pragma unroll
    for (int c = 0; c < 6; ++c) {
      float4 hh = h4[lane16 + 16 * c];          // contiguous 16B/lane: conflict-free
      h2[2 * c]     = f32x2{hh.x, hh.y};
      h2[2 * c + 1] = f32x2{hh.z, hh.w};
    }
  }
  float4 zz[3];
  if (!FULL) {
    const float4* z4 = (const float4*)zsh;
#pragma unroll
    for (int c = 0; c < 3; ++c) zz[c] = z4[lane16 + 16 * c];
  }
#pragma unroll 2
  for (int p = 0; p < 8; ++p) {
    const int r = p * NG + g;
    f32x2 acc0 = {0.f, 0.f}, acc1 = {0.f, 0.f};
    float gzv = 0.f;
    if (FULL) {
      if (lane16 == 0) gzv = gzrow[r];
    } else {
      const float4* wg = (const float4*)Wg_f + (size_t)r * (DG / 4);
#pragma unroll
      for (int c = 0; c < 3; ++c) {
        float4 w = wg[lane16 + 16 * c];
        acc0 = pkfma(f32x2{w.x, w.y}, f32x2{zz[c].x, zz[c].y}, acc0);
        acc1 = pkfma(f32x2{w.z, w.w}, f32x2{zz[c].z, zz[c].w}, acc1);
      }
    }
    if (with_h) {
      if (FULL) {
        const uint2* wh = (const uint2*)Wh_b + (size_t)r * (DH / 4);  // 96 uint2/row
#pragma unroll
        for (int c = 0; c < 6; ++c) {
          uint2 u = wh[lane16 + 16 * c];
          acc0 = pkfma(f32x2{blo(u.x), bhi(u.x)}, h2[2 * c], acc0);
          acc1 = pkfma(f32x2{blo(u.y), bhi(u.y)}, h2[2 * c + 1], acc1);
        }
      } else {
        const float4* wh = (const float4*)Wh_f + (size_t)r * (DH / 4);
#pragma unroll
        for (int c = 0; c < 6; ++c) {
          float4 w = wh[lane16 + 16 * c];
          acc0 = pkfma(f32x2{w.x, w.y}, h2[2 * c], acc0);
          acc1 = pkfma(f32x2{w.z, w.w}, h2[2 * c + 1], acc1);
        }
      }
    }
    float accs = row16_sum((acc0.x + acc1.x) + (acc0.y + acc1.y));
    if (lane16 == 0) {
      float vv = accs + (FULL ? gzv : bias[p]);
      hbs[r] = vv;
      s1 += vv;
      s2 += vv * vv;
    }
  }
}

template <bool FULL>
__global__ __launch_bounds__(NT) void fw_rnn_kernel(
    const float* __restrict__ z_seq,    // [T, B, DG]
    const float* __restrict__ Wh_f,     // [DH, DH] fp32
    const float* __restrict__ Wg_f,     // [DH, DG] fp32
    const ushort_t* __restrict__ Wh_b,  // bf16 copy (ws), FULL only
    const float* __restrict__ gz,       // [T, B, DH] precomputed Wg.z + b_h, FULL only
    const float* __restrict__ b_h,
    const float* __restrict__ ln_g,
    const float* __restrict__ ln_b,
    const float* __restrict__ alpha_fw,
    float* __restrict__ out)            // [B, DH]
{
  __shared__ __align__(16) float hs[DH];
  __shared__ __align__(16) float hbs[DH];
  __shared__ __align__(16) float zsh[DG];   // !FULL only
  __shared__ float wlam[NSTEP];
  __shared__ __align__(16) float carr[NG];
  __shared__ __align__(16) float redA[NWAVE * 2];   // 24 floats
  __shared__ __align__(16) float redB[2][32];       // rows padded to 32; [30],[31]=0

  const int tid    = threadIdx.x;
  const int b      = blockIdx.x;
  const int lane   = tid & 63, wv = tid >> 6;
  const int g      = tid >> 4, lane16 = tid & 15;
  const bool owner = (tid < DH);
  const bool zst   = (!FULL) && (tid >= DH) && (tid < DH + DG / 4);

  float bias[8];
#pragma unroll
  for (int p = 0; p < 8; ++p) bias[p] = 0.f;
  if (!FULL && lane16 == 0) {
#pragma unroll
    for (int p = 0; p < 8; ++p) bias[p] = b_h[p * NG + g];
  }
  float g_i = 0.f, be_i = 0.f;
  if (owner) { g_i = ln_g[tid]; be_i = ln_b[tid]; }

  const float af   = alpha_fw[0];
  const float kcur = (af >= 0.f) ? (1.f + log1pf(expf(af)))
                                 : (1.f / (1.f + log1pf(expf(-af))));
  const float invD = 1.0f / (float)DH;

  // Register-resident history column: hcol[tau] == h_committed[tau][tid] (owners).
  float hcol[48];
#pragma unroll
  for (int q = 0; q < 48; ++q) hcol[q] = 0.f;
  // Register-resident history row for this thread's 16-lane group (phase A).
  float4 hreg[6];
#pragma unroll
  for (int c = 0; c < 6; ++c) hreg[c] = float4{0.f, 0.f, 0.f, 0.f};

  if (!FULL && tid < DG / 4)
    ((float4*)zsh)[tid] = ((const float4*)(z_seq + (size_t)b * DG))[tid];
  if (tid < NG) carr[tid] = 0.f;  // entries >= t stay 0 for the 48-wide phase-B dot
  if (tid < 2) { redB[tid][30] = 0.f; redB[tid][31] = 0.f; }
  __syncthreads();

  float Shb = 0.f, Shb2 = 0.f;

  for (int t = 0; t < NSTEP; ++t) {
    // snapshot this group's committed row (hs == h_{t-1} until after barrier (a))
    if (t > 0 && g == t - 1) {
#pragma unroll
      for (int c = 0; c < 6; ++c) hreg[c] = ((const float4*)hs)[lane16 + 16 * c];
    }
    // ---------- base phase: h_base + fused LN stats ----------
    float s1 = 0.f, s2 = 0.f;
    matvec<FULL>(Wh_f, Wg_f, Wh_b, hs, zsh,
                 FULL ? gz + ((size_t)t * BB + b) * DH : nullptr,
                 bias, hbs, s1, s2, g, lane16, t > 0);
    {
      float v0 = wave_sum63(s1);
      float v1 = wave_sum63(s2);
      if (lane == 63) { redA[wv * 2] = v0; redA[wv * 2 + 1] = v1; }
    }
    __syncthreads();  // (a): hbs + redA visible

    float hb = 0.f, hsv = 0.f;
    if (owner) {
      float S1 = 0.f, S2 = 0.f;
      const float4* ra4 = (const float4*)redA;
#pragma unroll
      for (int q = 0; q < 6; ++q) {
        float4 ch = ra4[q];
        S1 += ch.x + ch.z;
        S2 += ch.y + ch.w;
      }
      Shb = S1; Shb2 = S2;
      hb = hbs[tid];
      float m   = S1 * invD;
      float var = S2 * invD - m * m;
      hsv = fmaxf((hb - m) * rsqrtf(var + 1e-5f) * g_i + be_i, 0.f);
      hs[tid] = hsv;
    }
    if (t == 0) {
      // A == 0: settling is identity. Commit, init wlam, stage z_1 (!FULL).
      if (owner) hcol[0] = hsv;
      if (tid == 0) wlam[0] = 0.5f;
      if (zst)
        ((float4*)zsh)[tid - DH] =
            ((const float4*)(z_seq + ((size_t)1 * BB + b) * DG))[tid - DH];
      __syncthreads();  // (b)
      continue;
    }
    __syncthreads();  // (b): hs visible

    float4 znext;
    if (zst)
      znext = ((const float4*)(z_seq + ((size_t)(t + 1) * BB + b) * DG))[tid - DH];

    // ---------- settling iterations ----------
    for (int s = 0; s < SETI; ++s) {
      // phase A: carr[tau] = wlam_tau * (h_tau . h_s); group g = tau, row in regs
      if (g < t) {
        const float4* s4 = (const float4*)hs;
        f32x2 p0 = {0.f, 0.f}, p1 = {0.f, 0.f};
#pragma unroll
        for (int c = 0; c < 6; ++c) {
          float4 ss = s4[lane16 + 16 * c];
          p0 = pkfma(f32x2{hreg[c].x, hreg[c].y}, f32x2{ss.x, ss.y}, p0);
          p1 = pkfma(f32x2{hreg[c].z, hreg[c].w}, f32x2{ss.z, ss.w}, p1);
        }
        float p = row16_sum((p0.x + p1.x) + (p0.y + p1.y));
        if (lane16 == 0) carr[g] = p * wlam[g];
      }
      __syncthreads();  // (i): carr visible

      // phase B: owners compute Ah from registers + 5 partial sums via DPP
      float ah = 0.f;
      if (owner) {
        const float4* c4 = (const float4*)carr;
        float ah0 = 0.f, ah1 = 0.f, ah2 = 0.f, ah3 = 0.f;
#pragma unroll
        for (int q = 0; q < 12; ++q) {
          float4 c = c4[q];
          ah0 = fmaf(c.x, hcol[4 * q + 0], ah0);
          ah1 = fmaf(c.y, hcol[4 * q + 1], ah1);
          ah2 = fmaf(c.z, hcol[4 * q + 2], ah2);
          ah3 = fmaf(c.w, hcol[4 * q + 3], ah3);
        }
        ah = (ah0 + ah2) + (ah1 + ah3);
        float v0 = wave_sum63(hsv * ah);
        float v1 = wave_sum63(hsv * hsv);
        float v2 = wave_sum63(ah * ah);
        float v3 = wave_sum63(hb * ah);
        float v4 = wave_sum63(ah);
        if (lane == 63) {
          float* rb = redB[s & 1];
          rb[wv * 5 + 0] = v0; rb[wv * 5 + 1] = v1; rb[wv * 5 + 2] = v2;
          rb[wv * 5 + 3] = v3; rb[wv * 5 + 4] = v4;
        }
      }
      __syncthreads();  // (ii): redB visible

      // phase C: gate + analytic LN + commit
      if (owner) {
        const float4* rb4 = (const float4*)redB[s & 1];
        float S[5] = {0.f, 0.f, 0.f, 0.f, 0.f};
#pragma unroll
        for (int q = 0; q < 8; ++q) {
          float4 ch = rb4[q];
          S[(4 * q + 0) % 5] += ch.x;
          S[(4 * q + 1) % 5] += ch.y;
          S[(4 * q + 2) % 5] += ch.z;
          S[(4 * q + 3) % 5] += ch.w;
        }
        float n1 = fmaxf(sqrtf(S[1]), 1e-6f);
        float n2 = fmaxf(sqrtf(S[2]), 1e-6f);
        float R  = fminf(fmaxf(__fdividef(S[0], n1 * n2), 0.f), 1.f);
        float a  = 1.f - __expf(kcur * __logf(1.f - R));
        float beta = 1.f - a * a;
        float mu  = (beta * Shb + a * S[4]) * invD;
        float Exx = (beta * beta * Shb2 + 2.f * beta * a * S[3] + a * a * S[2]) * invD;
        float var = Exx - mu * mu;
        float xv  = beta * hb + a * ah;
        hsv = fmaxf((xv - mu) * rsqrtf(var + 1e-5f) * g_i + be_i, 0.f);
        hs[tid] = hsv;
        if (s == SETI - 1) {
#pragma unroll
          for (int q = 0; q < 48; ++q)
            if (q == t) hcol[q] = hsv;
        }
      }
      if (s == SETI - 1) {
        if (tid < t) wlam[tid] *= 0.9f;
        else if (tid == t) wlam[tid] = 0.5f;
        if (zst) ((float4*)zsh)[tid - DH] = znext;
      }
      __syncthreads();  // (iii)
    }
  }

  // ================= final (query) step =================
  {
    if (g == NSTEP - 1) {   // last committed row -> regs
#pragma unroll
      for (int c = 0; c < 6; ++c) hreg[c] = ((const float4*)hs)[lane16 + 16 * c];
    }
    float s1 = 0.f, s2 = 0.f;
    matvec<FULL>(Wh_f, Wg_f, Wh_b, hs, zsh,
                 FULL ? gz + ((size_t)NSTEP * BB + b) * DH : nullptr,
                 bias, hbs, s1, s2, g, lane16, true);
    {
      float v0 = wave_sum63(s1);
      float v1 = wave_sum63(s2);
      if (lane == 63) { redA[wv * 2] = v0; redA[wv * 2 + 1] = v1; }
    }
    __syncthreads();

    float hb = 0.f, hv = 0.f;
    if (owner) {
      float S1 = 0.f, S2 = 0.f;
      const float4* ra4 = (const float4*)redA;
#pragma unroll
      for (int q = 0; q < 6; ++q) {
        float4 ch = ra4[q];
        S1 += ch.x + ch.z;
        S2 += ch.y + ch.w;
      }
      Shb = S1; Shb2 = S2;
      hb = hbs[tid];
      float m   = S1 * invD;
      float var = S2 * invD - m * m;
      hv = fmaxf((hb - m) * rsqrtf(var + 1e-5f) * g_i + be_i, 0.f);
      hs[tid] = hv;
    }
    __syncthreads();

    for (int s = 0; s < SETI; ++s) {
      if (g < NSTEP) {
        const float4* s4 = (const float4*)hs;
        f32x2 p0 = {0.f, 0.f}, p1 = {0.f, 0.f};
#pragma unroll
        for (int c = 0; c < 6; ++c) {
          float4 ss = s4[lane16 + 16 * c];
          p0 = pkfma(f32x2{hreg[c].x, hreg[c].y}, f32x2{ss.x, ss.y}, p0);
          p1 = pkfma(f32x2{hreg[c].z, hreg[c].w}, f32x2{ss.z, ss.w}, p1);
        }
        float p = row16_sum((p0.x + p1.x) + (p0.y + p1.y));
        if (lane16 == 0) carr[g] = p * wlam[g];
      }
      __syncthreads();

      float ah = 0.f;
      if (owner) {
        const float4* c4 = (const float4*)carr;
        float ah0 = 0.f, ah1 = 0.f, ah2 = 0.f, ah3 = 0.f;
#pragma unroll
        for (int q = 0; q < 12; ++q) {
          float4 c = c4[q];
          ah0 = fmaf(c.x, hcol[4 * q + 0], ah0);
          ah1 = fmaf(c.y, hcol[4 * q + 1], ah1);
          ah2 = fmaf(c.z, hcol[4 * q + 2], ah2);
          ah3 = fmaf(c.w, hcol[4 * q + 3], ah3);
        }
        ah = (ah0 + ah2) + (ah1 + ah3);
        float v0 = wave_sum63(ah);
        float v1 = wave_sum63(ah * ah);
        float v2 = wave_sum63(hb * ah);
        if (lane == 63) {
          float* rb = redB[s & 1];
          rb[wv * 5 + 0] = v0; rb[wv * 5 + 1] = v1; rb[wv * 5 + 2] = v2;
        }
      }
      __syncthreads();

      if (owner) {
        const float4* rb4 = (const float4*)redB[s & 1];
        float S[5] = {0.f, 0.f, 0.f, 0.f, 0.f};
#pragma unroll
        for (int q = 0; q < 8; ++q) {
          float4 ch = rb4[q];
          S[(4 * q + 0) % 5] += ch.x;
          S[(4 * q + 1) % 5] += ch.y;
          S[(4 * q + 2) % 5] += ch.z;
          S[(4 * q + 3) % 5] += ch.w;
        }
        // xv = hb + ah : analytic stats (S[0]=sum ah, S[1]=sum ah^2, S[2]=sum hb*ah)
        float Sx  = Shb + S[0];
        float Sxx = Shb2 + 2.f * S[2] + S[1];
        float mu  = Sx * invD;
        float var = Sxx * invD - mu * mu;
        float xv  = hb + ah;
        hv = fmaxf((xv - mu) * rsqrtf(var + 1e-5f) * g_i + be_i, 0.f);
        if (s < SETI - 1) hs[tid] = hv;
      }
      if (s < SETI - 1) __syncthreads();
    }

    if (owner) out[(size_t)b * DH + tid] = hv;
  }
}

// Prologue: gz[t][b][r] = bf16(W_g)[r,:] . z[t][b] + b_h[r]  (parallel over t,b)
__global__ __launch_bounds__(NT) void gz_kernel(
    const float* __restrict__ z_seq, const ushort_t* __restrict__ Wg_b,
    const float* __restrict__ b_h, float* __restrict__ gz)
{
  __shared__ __align__(16) float zsh[DG];
  const int tid = threadIdx.x, b = blockIdx.x, t = blockIdx.y;
  const int g = tid >> 4, lane16 = tid & 15;
  if (tid < DG / 4)
    ((float4*)zsh)[tid] = ((const float4*)(z_seq + ((size_t)t * BB + b) * DG))[tid];
  __syncthreads();
  float4 zz[3];
  const float4* z4 = (const float4*)zsh;
#pragma unroll
  for (int c = 0; c < 3; ++c) zz[c] = z4[lane16 + 16 * c];
  float* grow = gz + ((size_t)t * BB + b) * DH;
#pragma unroll
  for (int p = 0; p < 8; ++p) {
    const int r = p * NG + g;
    const uint2* wg = (const uint2*)Wg_b + (size_t)r * (DG / 4);  // 48 uint2/row
    f32x2 acc0 = {0.f, 0.f}, acc1 = {0.f, 0.f};
#pragma unroll
    for (int c = 0; c < 3; ++c) {
      uint2 u = wg[lane16 + 16 * c];
      acc0 = pkfma(f32x2{blo(u.x), bhi(u.x)}, f32x2{zz[c].x, zz[c].y}, acc0);
      acc1 = pkfma(f32x2{blo(u.y), bhi(u.y)}, f32x2{zz[c].z, zz[c].w}, acc1);
    }
    float a = row16_sum((acc0.x + acc1.x) + (acc0.y + acc1.y));
    if (lane16 == 0) grow[r] = a + b_h[r];
  }
}

// fp32 -> bf16 (RTN-even) conversion for W matrices
__global__ void cvt_kernel(const float* __restrict__ src,
                           ushort_t* __restrict__ dst, int n) {
  int i = blockIdx.x * blockDim.x + threadIdx.x;
  if (i < n) {
    unsigned u = __float_as_uint(src[i]);
    unsigned r = (u + 0x7FFFu + ((u >> 16) & 1u)) >> 16;
    dst[i] = (ushort_t)r;
  }
}

extern "C" void kernel_launch(void* const* d_in, const int* in_sizes, int n_in,
                              void* d_out, int out_size, void* d_ws, size_t ws_size,
                              hipStream_t stream) {
  const float* z_seq    = (const float*)d_in[0];
  const float* W_h      = (const float*)d_in[1];
  const float* W_g      = (const float*)d_in[2];
  const float* b_h      = (const float*)d_in[3];
  const float* ln_g     = (const float*)d_in[4];
  const float* ln_b     = (const float*)d_in[5];
  const float* alpha_fw = (const float*)d_in[6];
  float* out = (float*)d_out;

  const size_t nWh = (size_t)DH * DH;  // 147456
  const size_t nWg = (size_t)DH * DG;  // 73728
  const size_t bf16Bytes = (nWh + nWg) * sizeof(ushort_t);       // 442368
  const size_t gzBytes   = (size_t)TT * BB * DH * sizeof(float); // 7077888

  if (ws_size >= bf16Bytes + gzBytes) {
    ushort_t* Whb = (ushort_t*)d_ws;
    ushort_t* Wgb = Whb + nWh;
    float* gz = (float*)((char*)d_ws + bf16Bytes);
    cvt_kernel<<<dim3((int)((nWh + 255) / 256)), dim3(256), 0, stream>>>(
        W_h, Whb, (int)nWh);
    cvt_kernel<<<dim3((int)((nWg + 255) / 256)), dim3(256), 0, stream>>>(
        W_g, Wgb, (int)nWg);
    gz_kernel<<<dim3(BB, TT), dim3(NT), 0, stream>>>(z_seq, Wgb, b_h, gz);
    fw_rnn_kernel<true><<<dim3(BB), dim3(NT), 0, stream>>>(
        z_seq, W_h, W_g, Whb, gz, b_h, ln_g, ln_b, alpha_fw, out);
  } else {
    fw_rnn_kernel<false><<<dim3(BB), dim3(NT), 0, stream>>>(
        z_seq, W_h, W_g, nullptr, nullptr, b_h, ln_g, ln_b, alpha_fw, out);
  }
}